// Round 9
// baseline (604.859 us; speedup 1.0000x reference)
//
#include <hip/hip_runtime.h>

typedef _Float16 f16;
typedef _Float16 f16x8 __attribute__((ext_vector_type(8)));
typedef float f32x4 __attribute__((ext_vector_type(4)));
typedef float f32x16 __attribute__((ext_vector_type(16)));

#define NB 32
#define NT 512
#define ND 256
#define NH 512
#define NK 8
#define M_REAL 16352   // NB*(NT-1)
#define M_PAD 16384
#define RDIM 768       // ND + NH
#define TILE_ELEMS 98304  // 96 ch * 128 rows * 8 f16 per tile

// output offsets (floats)
#define OFF_PI 0
#define OFF_S  256
#define OFF_H  1048832
#define OFF_Y  1179904
#define OFF_G1 1196288
#define OFF_G2 1327360
#define OFF_F  2373888
#define OFF_BW 2504960

// ws offsets (bytes)
#define WS_A    0            // f16 tiled [128][96][128][8] = 25165824 B ; reused as PsT after gemm
#define WS_B    25165824     // f16 tiled [32][96][128][8]  = 6291456 B
#define WS_BIAS 31457280     // f32 [4096]
#define WS_NEED 31473664

#define CH_CONST 1887.3506062251f   // -0.5*512*(log(2pi)+log(1e-4))
#define CY_CONST 943.6753031126f    // -0.5*256*(...)
#define LOG2E 1.4426950408889634f
#define LN2 0.6931471805599453f

__device__ __forceinline__ float fexp2(float x) { return __builtin_amdgcn_exp2f(x); }
__device__ __forceinline__ float flog2(float x) { return __builtin_amdgcn_logf(x); }
__device__ __forceinline__ float ftanh(float x) {
    x = fminf(10.f, fmaxf(-10.f, x));
    float t = fexp2(x * 2.885390081777927f);  // 2*log2(e)
    return (t - 1.f) * __builtin_amdgcn_rcpf(t + 1.f);
}
__device__ __forceinline__ float lse8v(const float* z) {
    float M = fmaxf(fmaxf(fmaxf(z[0], z[1]), fmaxf(z[2], z[3])),
                    fmaxf(fmaxf(z[4], z[5]), fmaxf(z[6], z[7])));
    float s = 0.f;
#pragma unroll
    for (int j = 0; j < 8; ++j) s += fexp2((z[j] - M) * LOG2E);
    return M + LN2 * flog2(s);
}

// =================== pre_kernel: everything independent of the GEMM ===========
// branch by blockIdx (block-uniform): conv_a | conv_b | emission | trans | init.
// One 64 KB LDS arena reused per branch (trans needs all of it).
__global__ __launch_bounds__(256) void pre_kernel(
    const float* __restrict__ x, const float* __restrict__ h, const float* __restrict__ y,
    const float* __restrict__ initials, const float* __restrict__ Wih,
    const float* __restrict__ Whh, const float* __restrict__ bih,
    const float* __restrict__ bhh, const float* __restrict__ Wt,
    const float* __restrict__ btv, const float* __restrict__ W1,
    const float* __restrict__ b1, const float* __restrict__ W2,
    const float* __restrict__ b2, const float* __restrict__ W3,
    const float* __restrict__ b3, f16* __restrict__ A, f16* __restrict__ Bm,
    float* __restrict__ biasc, float* __restrict__ PsT, float* __restrict__ out) {
    __shared__ __align__(16) float smem[16384];  // 64 KB arena
    const int tid = threadIdx.x;
    const int blk = blockIdx.x;

    if (blk < 6144) {  // -------- conv_a: A tiled f16 --------
        const int g = blk * 256 + tid;  // < 16384*96
        const int m = g / 96;
        const int ch = g - m * 96;
        f16x8 pk = (f16x8)(f16)0.f;
        if (m < M_REAL) {
            const int b = m / 511;
            const int t = m - b * 511;
            const int c0 = ch * 8;
            const float* src = (c0 < ND) ? x + (size_t)(b * NT + t + 1) * ND + c0
                                         : h + (size_t)(b * NT + t) * NH + (c0 - ND);
            const float4 u = ((const float4*)src)[0];
            const float4 v = ((const float4*)src)[1];
            pk[0] = (f16)u.x; pk[1] = (f16)u.y; pk[2] = (f16)u.z; pk[3] = (f16)u.w;
            pk[4] = (f16)v.x; pk[5] = (f16)v.y; pk[6] = (f16)v.z; pk[7] = (f16)v.w;
        }
        const size_t dst =
            (size_t)(m >> 7) * TILE_ELEMS + (size_t)ch * 1024 + (size_t)(m & 127) * 8;
        *(f16x8*)(A + dst) = pk;
    } else if (blk < 7680) {  // -------- conv_b --------
        const int g = (blk - 6144) * 256 + tid;  // < 4096*96
        const int n = g / 96;
        const int ch = g - n * 96;
        const int c0 = ch * 8;
        const float* src =
            (c0 < ND) ? Wih + (size_t)n * ND + c0 : Whh + (size_t)n * NH + (c0 - ND);
        const float4 u = ((const float4*)src)[0];
        const float4 v = ((const float4*)src)[1];
        f16x8 pk;
        pk[0] = (f16)u.x; pk[1] = (f16)u.y; pk[2] = (f16)u.z; pk[3] = (f16)u.w;
        pk[4] = (f16)v.x; pk[5] = (f16)v.y; pk[6] = (f16)v.z; pk[7] = (f16)v.w;
        const size_t dst =
            (size_t)(n >> 7) * TILE_ELEMS + (size_t)ch * 1024 + (size_t)(n & 127) * 8;
        *(f16x8*)(Bm + dst) = pk;
        if (ch == 0) biasc[n] = bih[n] + bhh[n];
    } else if (blk < 8704) {  // -------- emission MLP + gaussian lp --------
        float* ssh = smem;             // 16*512
        float* W2sh = smem + 8192;     // 64*33
        float* h1sh = smem + 10304;    // 16*32
        float* h2sh = smem + 10816;    // 16*64
        float* red = smem + 11840;     // 16*4
        const int wv = tid >> 6;
        const int o = tid >> 3, seg = tid & 7;
        const int p0 = (blk - 7680) * 16;
        float4 w1r[16], w3r[16];
        {
            const float4* w1p = (const float4*)(W1 + (size_t)o * NH + seg * 64);
#pragma unroll
            for (int j = 0; j < 16; ++j) w1r[j] = w1p[(j + seg * 2) & 15];  // staggered load
            const float4* w3p = (const float4*)(W3 + (size_t)tid * 64);
#pragma unroll
            for (int j = 0; j < 16; ++j) w3r[j] = w3p[j];
        }
        if (tid < 64) {
            for (int j = 0; j < 32; ++j) W2sh[tid * 33 + j] = W2[tid * 32 + j];
        }
        float yv[16];
#pragma unroll
        for (int pp = 0; pp < 16; ++pp) yv[pp] = y[(size_t)(p0 + pp) * ND + tid];
        const float b1r = b1[o];
        const float b2r = b2[tid & 63];
        const float b3r = b3[tid];
#pragma unroll
        for (int pp = 0; pp < 16; ++pp) {
            const float2 hv = ((const float2*)(h + (size_t)(p0 + pp) * NH))[tid];
            ssh[pp * 512 + tid * 2] = hv.x;
            ssh[pp * 512 + tid * 2 + 1] = hv.y;
        }
        __syncthreads();
#pragma unroll
        for (int pp = 0; pp < 16; ++pp) {
            const float4* s4 = (const float4*)&ssh[pp * 512 + seg * 64];
            float p = 0.f;
#pragma unroll
            for (int it = 0; it < 16; ++it) {
                const float4 sv = s4[(it + seg * 2) & 15];  // dynamic LDS idx ok
                const float4 w = w1r[it];                   // static reg idx
                p += w.x * sv.x + w.y * sv.y + w.z * sv.z + w.w * sv.w;
            }
            p += __shfl_xor(p, 1, 64);
            p += __shfl_xor(p, 2, 64);
            p += __shfl_xor(p, 4, 64);
            if (seg == 0) h1sh[pp * 32 + o] = fmaxf(p + b1r, 0.f);
        }
        __syncthreads();
        {
            const int o2 = tid & 63;
#pragma unroll
            for (int it = 0; it < 4; ++it) {
                const int pp = wv * 4 + it;
                float s = b2r;
#pragma unroll
                for (int j = 0; j < 32; ++j) s += W2sh[o2 * 33 + j] * h1sh[pp * 32 + j];
                h2sh[pp * 64 + o2] = fmaxf(s, 0.f);
            }
        }
        __syncthreads();
#pragma unroll
        for (int pp = 0; pp < 16; ++pp) {
            float s = b3r;
            const float4* h24 = (const float4*)&h2sh[pp * 64];
#pragma unroll
            for (int j = 0; j < 16; ++j) {
                const float4 w = w3r[j], hb = h24[j];
                s += w.x * hb.x + w.y * hb.y + w.z * hb.z + w.w * hb.w;
            }
            const float d = yv[pp] - s;
            float sq = d * d;
#pragma unroll
            for (int off = 32; off > 0; off >>= 1) sq += __shfl_xor(sq, off, 64);
            if ((tid & 63) == 0) red[pp * 4 + wv] = sq;
        }
        __syncthreads();
        if (tid < 16) {
            out[OFF_Y + p0 + tid] =
                CY_CONST - 5000.f * (red[tid * 4] + red[tid * 4 + 1] + red[tid * 4 + 2] +
                                     red[tid * 4 + 3]);
        }
    } else if (blk < 9215) {  // -------- trans + column log-softmax --------
        float* hsh = smem;  // 32*512 = 64 KB
        const int lane = tid & 63;
        const int wave = tid >> 6;
        const int mbase = (blk - 8704) * 32 + wave * 8;
#pragma unroll
        for (int r = 0; r < 8; ++r) {
            const int m = mbase + r;
            const int b = m / 511, t = m - b * 511;
            const float4* src = (const float4*)(h + (size_t)(b * NT + t) * NH);
            ((float4*)&hsh[(wave * 8 + r) * 512])[lane] = src[lane];
            ((float4*)&hsh[(wave * 8 + r) * 512])[lane + 64] = src[lane + 64];
        }
        __syncthreads();
        const int c = lane;  // output index = i*8 + j
        float acc[8];
#pragma unroll
        for (int r = 0; r < 8; ++r) acc[r] = btv[c];
        const float4* w4 = (const float4*)(Wt + (size_t)c * NH);
        for (int hh = 0; hh < 128; ++hh) {
            const float4 w = w4[hh];
#pragma unroll
            for (int r = 0; r < 8; ++r) {
                const float4 hv = ((const float4*)&hsh[(wave * 8 + r) * 512])[hh];
                acc[r] += w.x * hv.x + w.y * hv.y + w.z * hv.z + w.w * hv.w;
            }
        }
#pragma unroll
        for (int r = 0; r < 8; ++r) {
            const float tr = ftanh(acc[r]);
            float M = tr;
            M = fmaxf(M, __shfl_xor(M, 8, 64));
            M = fmaxf(M, __shfl_xor(M, 16, 64));
            M = fmaxf(M, __shfl_xor(M, 32, 64));
            float s = fexp2((tr - M) * LOG2E);
            s += __shfl_xor(s, 8, 64);
            s += __shfl_xor(s, 16, 64);
            s += __shfl_xor(s, 32, 64);
            const float lse = M + LN2 * flog2(s);
            const int m = mbase + r;
            const int b = m / 511, t = m - b * 511;
            const float v = tr - lse;
            out[OFF_S + (size_t)(b * NT + t + 1) * 64 + c] = v;
            PsT[(size_t)(b * NT + t + 1) * 64 + (c & 7) * 8 + (c >> 3)] = v;
        }
    } else {  // -------- init: Ph=CH_CONST (gemm atomically accumulates), s0, pinit
        const int g = (blk - 9215) * 256 + tid;  // < 131072
        out[OFF_H + g] = CH_CONST;
        if (g < 2048) {
            const int sb = g >> 6, c = g & 63;
            out[OFF_S + (size_t)sb * NT * 64 + c] = ((c >> 3) == (c & 7)) ? 1.f : 0.f;
        }
        if (g < 256) {
            float z[8];
#pragma unroll
            for (int j = 0; j < 8; ++j) z[j] = initials[j];
            out[OFF_PI + g] = z[g & 7] - lse8v(z);
        }
    }
}

// ------- big GEMM (32x32x16 MFMA, R6-exact staging) + tanh + atomic sq epilogue
// K-loop kept at the R6 local optimum: single-buffer global_load_lds, A-panels
// pinned per XCD (3 MB L2-resident). Pipelining attempts all regressed:
// LDS-dbuf (R5, occupancy), fixed-B swizzle (R7, A streamed 8x), reg-prefetch
// (R8, FETCH +130 MB). Epilogue: atomicAdd(-5000*rs) straight into Ph
// (pre-initialized to CH_CONST) — drops sq_part + the finalize kernel.
__global__ __launch_bounds__(256) void gemm_kernel(const f16* __restrict__ A,
                                                   const f16* __restrict__ Bm,
                                                   const float* __restrict__ biasc,
                                                   const float* __restrict__ sampled_h,
                                                   float* __restrict__ Ph) {
    __shared__ __align__(16) f16 Ash[8 * 128 * 8];
    __shared__ __align__(16) f16 Bsh[8 * 128 * 8];
    const int tid = threadIdx.x;
    const int lane = tid & 63;
    const int wave = tid >> 6;
    const int wx = wave & 1, wy = wave >> 1;
    const int xcd = blockIdx.x & 7;
    const int slot = blockIdx.x >> 3;
    const int tm = xcd * 16 + (slot >> 5);
    const int tn = slot & 31;
    const int m0 = tm * 128, n0 = tn * 128;
    const int l31 = lane & 31, hk = lane >> 5;

    f32x16 acc[2][2];
#pragma unroll
    for (int a = 0; a < 2; ++a)
#pragma unroll
        for (int b = 0; b < 2; ++b) acc[a][b] = (f32x16)0.f;

    for (int kk = 0; kk < RDIM; kk += 64) {
        __syncthreads();
        const size_t abase = (size_t)tm * TILE_ELEMS + (size_t)kk * 128;
        const size_t bbase = (size_t)tn * TILE_ELEMS + (size_t)kk * 128;
#pragma unroll
        for (int inst = 0; inst < 4; ++inst) {
            const int fb = inst * 256 + wave * 64;  // wave-uniform
            const f16* ga = A + abase + (size_t)(fb + lane) * 8;  // contiguous 1KB/inst
            const f16* gb = Bm + bbase + (size_t)(fb + lane) * 8;
            __builtin_amdgcn_global_load_lds(
                (const __attribute__((address_space(1))) void*)ga,
                (__attribute__((address_space(3))) void*)&Ash[fb * 8], 16, 0, 0);
            __builtin_amdgcn_global_load_lds(
                (const __attribute__((address_space(1))) void*)gb,
                (__attribute__((address_space(3))) void*)&Bsh[fb * 8], 16, 0, 0);
        }
        __syncthreads();
#pragma unroll
        for (int kc = 0; kc < 4; ++kc) {
            const int ch = kc * 2 + hk;
            f16x8 af[2], bfr[2];
#pragma unroll
            for (int mi = 0; mi < 2; ++mi)
                af[mi] = *(const f16x8*)&Ash[(ch * 128 + wy * 64 + mi * 32 + l31) * 8];
#pragma unroll
            for (int ni = 0; ni < 2; ++ni)
                bfr[ni] = *(const f16x8*)&Bsh[(ch * 128 + wx * 64 + ni * 32 + l31) * 8];
#pragma unroll
            for (int mi = 0; mi < 2; ++mi)
#pragma unroll
                for (int ni = 0; ni < 2; ++ni)
                    acc[mi][ni] = __builtin_amdgcn_mfma_f32_32x32x16_f16(af[mi], bfr[ni],
                                                                         acc[mi][ni], 0, 0, 0);
        }
    }

    // epilogue: C layout col=lane&31, row=(reg&3)+8*(reg>>2)+4*(lane>>5)
    const int nbase = n0 + wx * 64;
    const int k0 = n0 >> 9;
    const float bias0 = biasc[nbase + l31];
    const float bias1 = biasc[nbase + 32 + l31];
#pragma unroll
    for (int mi = 0; mi < 2; ++mi) {
#pragma unroll
        for (int r = 0; r < 16; ++r) {
            const int mg = m0 + wy * 64 + mi * 32 + (r & 3) + 8 * (r >> 2) + 4 * hk;
            if (mg < M_REAL) {
                const int bb = mg / 511;
                const int tt = mg - bb * 511;
                const float* tgt = sampled_h + (size_t)((bb << 9) + tt + 1) * NH;
                float rs;
                {
                    const float v0 = ftanh(acc[mi][0][r] + bias0);
                    const float d0 = tgt[(nbase + l31) & 511] - v0;
                    const float v1 = ftanh(acc[mi][1][r] + bias1);
                    const float d1 = tgt[(nbase + 32 + l31) & 511] - v1;
                    rs = d0 * d0 + d1 * d1;
                }
                rs += __shfl_xor(rs, 1, 64);
                rs += __shfl_xor(rs, 2, 64);
                rs += __shfl_xor(rs, 4, 64);
                rs += __shfl_xor(rs, 8, 64);
                rs += __shfl_xor(rs, 16, 64);
                if (l31 == 0)
                    atomicAdd(&Ph[(size_t)(bb << 12) + (size_t)(tt + 1) * 8 + k0],
                              -5000.f * rs);
            }
        }
    }
}

// ------- forward / backward scans: shfl-only + depth-8 register pipeline -------
__global__ __launch_bounds__(256) void scan_kernel(const float* __restrict__ initials,
                                                   const float* __restrict__ PsT,
                                                   float* __restrict__ out) {
    const float* Ps = out + OFF_S;
    const float* Ph = out + OFF_H;
    const float* Py = out + OFF_Y;
    const int lane = threadIdx.x & 63;
    const int wave = threadIdx.x >> 6;
    const int b = wave * 8 + (lane >> 3);
    const int i = lane & 7;
    const int lbase = lane & ~7;

    if (blockIdx.x == 0) {
        float z0[8];
#pragma unroll
        for (int j = 0; j < 8; ++j) z0[j] = initials[j];
        float* Fw = out + OFF_F;
        float a = (z0[i] - lse8v(z0)) + CH_CONST + Py[b * NT];
        Fw[(size_t)(b * NT) * 8 + i] = a;
        float4 cA[8], cB[8]; float cH[8], cY[8];
        float4 nA[8], nB[8]; float nH[8], nY[8];
#define FLOAD(CC, A_, B_, H_, Y_)                                                  \
        _Pragma("unroll") for (int j = 0; j < 8; ++j) {                            \
            int t = 1 + (CC) * 8 + j;                                              \
            t = t > 511 ? 511 : t;                                                 \
            const size_t p = (size_t)(b * NT + t) * 64 + i * 8;                    \
            A_[j] = *(const float4*)&Ps[p];                                        \
            B_[j] = *(const float4*)&Ps[p + 4];                                    \
            H_[j] = Ph[(size_t)(b * NT + t) * 8 + i];                              \
            Y_[j] = Py[b * NT + t];                                                \
        }
#define FSTEP(CC, A_, B_, H_, Y_)                                                  \
        _Pragma("unroll") for (int j = 0; j < 8; ++j) {                            \
            const int t = 1 + (CC) * 8 + j;                                        \
            if (t < NT) {                                                          \
                float z[8];                                                        \
                z[0] = __shfl(a, lbase + 0, 64) + A_[j].x;                         \
                z[1] = __shfl(a, lbase + 1, 64) + A_[j].y;                         \
                z[2] = __shfl(a, lbase + 2, 64) + A_[j].z;                         \
                z[3] = __shfl(a, lbase + 3, 64) + A_[j].w;                         \
                z[4] = __shfl(a, lbase + 4, 64) + B_[j].x;                         \
                z[5] = __shfl(a, lbase + 5, 64) + B_[j].y;                         \
                z[6] = __shfl(a, lbase + 6, 64) + B_[j].z;                         \
                z[7] = __shfl(a, lbase + 7, 64) + B_[j].w;                         \
                a = (H_[j] + Y_[j]) + lse8v(z);                                    \
                Fw[(size_t)(b * NT + t) * 8 + i] = a;                              \
            }                                                                      \
        }
        FLOAD(0, cA, cB, cH, cY);
        for (int c = 0; c < 64; c += 2) {
            const int c1 = c + 1;
            const int c2 = (c + 2 < 64) ? c + 2 : 63;
            FLOAD(c1, nA, nB, nH, nY);
            FSTEP(c, cA, cB, cH, cY);
            FLOAD(c2, cA, cB, cH, cY);
            FSTEP(c1, nA, nB, nH, nY);
        }
#undef FLOAD
#undef FSTEP
    } else {
        float* Bw = out + OFF_BW;
        float bv = 0.f;
        Bw[(size_t)(b * NT + NT - 1) * 8 + i] = 0.f;
        float4 cA[8], cB[8]; float cH[8], cY[8];
        float4 nA[8], nB[8]; float nH[8], nY[8];
#define BLOAD(CC, A_, B_, H_, Y_)                                                  \
        _Pragma("unroll") for (int j = 0; j < 8; ++j) {                            \
            int t = 510 - ((CC) * 8 + j);                                          \
            t = t < 0 ? 0 : t;                                                     \
            const size_t t1 = (size_t)(b * NT + t + 1);                            \
            const size_t p = t1 * 64 + i * 8;                                      \
            A_[j] = *(const float4*)&PsT[p];                                       \
            B_[j] = *(const float4*)&PsT[p + 4];                                   \
            H_[j] = Ph[t1 * 8 + i];                                                \
            Y_[j] = Py[t1];                                                        \
        }
#define BSTEP(CC, A_, B_, H_, Y_)                                                  \
        _Pragma("unroll") for (int j = 0; j < 8; ++j) {                            \
            const int t = 510 - ((CC) * 8 + j);                                    \
            if (t >= 0) {                                                          \
                const float v = H_[j] + Y_[j] + bv;                                \
                float z[8];                                                        \
                z[0] = __shfl(v, lbase + 0, 64) + A_[j].x;                         \
                z[1] = __shfl(v, lbase + 1, 64) + A_[j].y;                         \
                z[2] = __shfl(v, lbase + 2, 64) + A_[j].z;                         \
                z[3] = __shfl(v, lbase + 3, 64) + A_[j].w;                         \
                z[4] = __shfl(v, lbase + 4, 64) + B_[j].x;                         \
                z[5] = __shfl(v, lbase + 5, 64) + B_[j].y;                         \
                z[6] = __shfl(v, lbase + 6, 64) + B_[j].z;                         \
                z[7] = __shfl(v, lbase + 7, 64) + B_[j].w;                         \
                bv = lse8v(z);                                                     \
                Bw[(size_t)(b * NT + t) * 8 + i] = bv;                             \
            }                                                                      \
        }
        BLOAD(0, cA, cB, cH, cY);
        for (int c = 0; c < 64; c += 2) {
            const int c1 = c + 1;
            const int c2 = (c + 2 < 64) ? c + 2 : 63;
            BLOAD(c1, nA, nB, nH, nY);
            BSTEP(c, cA, cB, cH, cY);
            BLOAD(c2, cA, cB, cH, cY);
            BSTEP(c1, nA, nB, nH, nY);
        }
#undef BLOAD
#undef BSTEP
    }
}

// ---------------- fused gamma2 (511 blocks) + gamma1 (64 blocks) ---------------
__global__ void gamma_kernel(float* __restrict__ out) {
    const float* Ps = out + OFF_S;
    const float* Ph = out + OFF_H;
    const float* Py = out + OFF_Y;
    const float* Fw = out + OFF_F;
    const float* Bw = out + OFF_BW;
    if (blockIdx.x < 511) {
        const int gidx = blockIdx.x * 256 + threadIdx.x;  // < 130816 = 32*511*8
        const int pos = gidx >> 3;                        // b*511 + t
        const int i = gidx & 7;
        const int b = pos / 511, t = pos - b * 511;
        const size_t t1 = (size_t)(b * NT + t + 1);
        const float ei = Ph[t1 * 8 + i] + Py[t1] + Bw[t1 * 8 + i];
        const float4 sa = ((const float4*)&Ps[(t1 * 8 + i) * 8])[0];
        const float4 sb = ((const float4*)&Ps[(t1 * 8 + i) * 8])[1];
        const float4 fa = ((const float4*)&Fw[(size_t)(b * NT + t) * 8])[0];
        const float4 fb = ((const float4*)&Fw[(size_t)(b * NT + t) * 8])[1];
        float z[8] = {fa.x + sa.x + ei, fa.y + sa.y + ei, fa.z + sa.z + ei, fa.w + sa.w + ei,
                      fb.x + sb.x + ei, fb.y + sb.y + ei, fb.z + sb.z + ei, fb.w + sb.w + ei};
        float M = fmaxf(fmaxf(fmaxf(z[0], z[1]), fmaxf(z[2], z[3])),
                        fmaxf(fmaxf(z[4], z[5]), fmaxf(z[6], z[7])));
        M = fmaxf(M, __shfl_xor(M, 1, 64));
        M = fmaxf(M, __shfl_xor(M, 2, 64));
        M = fmaxf(M, __shfl_xor(M, 4, 64));
        float s = 0.f;
#pragma unroll
        for (int j = 0; j < 8; ++j) s += fexp2((z[j] - M) * LOG2E);
        s += __shfl_xor(s, 1, 64);
        s += __shfl_xor(s, 2, 64);
        s += __shfl_xor(s, 4, 64);
        const float l = M + LN2 * flog2(s);
        float* G2 = out + OFF_G2;
        float4 o0 = {z[0] - l, z[1] - l, z[2] - l, z[3] - l};
        float4 o1 = {z[4] - l, z[5] - l, z[6] - l, z[7] - l};
        ((float4*)&G2[(size_t)gidx * 8])[0] = o0;
        ((float4*)&G2[(size_t)gidx * 8])[1] = o1;
    } else {
        const int pos = (blockIdx.x - 511) * 256 + threadIdx.x;  // < 16384
        const float4 fa = ((const float4*)&Fw[(size_t)pos * 8])[0];
        const float4 fb = ((const float4*)&Fw[(size_t)pos * 8])[1];
        const float4 ba = ((const float4*)&Bw[(size_t)pos * 8])[0];
        const float4 bb = ((const float4*)&Bw[(size_t)pos * 8])[1];
        float ab[8] = {fa.x + ba.x, fa.y + ba.y, fa.z + ba.z, fa.w + ba.w,
                       fb.x + bb.x, fb.y + bb.y, fb.z + bb.z, fb.w + bb.w};
        const float l = lse8v(ab);
        float* G1 = out + OFF_G1;
        float4 o0 = {ab[0] - l, ab[1] - l, ab[2] - l, ab[3] - l};
        float4 o1 = {ab[4] - l, ab[5] - l, ab[6] - l, ab[7] - l};
        ((float4*)&G1[(size_t)pos * 8])[0] = o0;
        ((float4*)&G1[(size_t)pos * 8])[1] = o1;
    }
}

extern "C" void kernel_launch(void* const* d_in, const int* in_sizes, int n_in, void* d_out,
                              int out_size, void* d_ws, size_t ws_size, hipStream_t stream) {
    const float* x = (const float*)d_in[0];
    const float* y = (const float*)d_in[1];
    const float* h = (const float*)d_in[2];
    const float* initials = (const float*)d_in[3];
    const float* Wih = (const float*)d_in[4];
    const float* Whh = (const float*)d_in[5];
    const float* bih = (const float*)d_in[6];
    const float* bhh = (const float*)d_in[7];
    const float* Wt = (const float*)d_in[8];
    const float* btv = (const float*)d_in[9];
    const float* W1 = (const float*)d_in[10];
    const float* b1 = (const float*)d_in[11];
    const float* W2 = (const float*)d_in[12];
    const float* b2 = (const float*)d_in[13];
    const float* W3 = (const float*)d_in[14];
    const float* b3 = (const float*)d_in[15];
    float* out = (float*)d_out;
    char* ws = (char*)d_ws;
    if (ws_size < (size_t)WS_NEED) return;
    f16* Aws = (f16*)(ws + WS_A);
    f16* Bws = (f16*)(ws + WS_B);
    float* biasc = (float*)(ws + WS_BIAS);
    float* PsT = (float*)(ws + WS_A);  // overlays A staging, but disjoint in time?
    // NOTE: PsT is written by pre (trans branch) and A by pre (conv_a branch) —
    // they must NOT overlap. Place PsT in the B-region tail instead? B is live
    // through gemm too. Use a dedicated region: put PsT after biasc.
    PsT = (float*)(ws + WS_BIAS + 16384);

    pre_kernel<<<9727, 256, 0, stream>>>(x, h, y, initials, Wih, Whh, bih, bhh, Wt, btv, W1,
                                         b1, W2, b2, W3, b3, Aws, Bws, biasc, PsT, out);
    gemm_kernel<<<4096, 256, 0, stream>>>(Aws, Bws, biasc, h, out + OFF_H);
    scan_kernel<<<2, 256, 0, stream>>>(initials, PsT, out);
    gamma_kernel<<<575, 256, 0, stream>>>(out);
}

// Round 10
// 560.256 us; speedup vs baseline: 1.0796x; 1.0796x over previous
//
#include <hip/hip_runtime.h>

typedef _Float16 f16;
typedef _Float16 f16x8 __attribute__((ext_vector_type(8)));
typedef float f32x16 __attribute__((ext_vector_type(16)));

#define NB 32
#define NT 512
#define ND 256
#define NH 512
#define M_REAL 16352   // NB*(NT-1)
#define RDIM 768       // ND + NH
#define TILE_ELEMS 98304  // 96 ch * 128 rows * 8 f16 per tile
#define NTN 33            // 32 real n-tiles + 1 trans tile (cols 4096..4223)

// output offsets (floats)
#define OFF_PI 0
#define OFF_S  256
#define OFF_H  1048832
#define OFF_Y  1179904
#define OFF_G1 1196288
#define OFF_G2 1327360
#define OFF_F  2373888
#define OFF_BW 2504960

// ws offsets (bytes)
#define WS_A    0            // f16 tiled [128][96][128][8] = 25165824 B
#define WS_B    25165824     // f16 tiled [33][96][128][8]  = 6488064 B
#define WS_BIAS 31653888     // f32 [4224] (pad 17408)
#define WS_SQ   31671296     // f32 [16384][8][4] = 2097152 B
#define WS_NEED 33768448

#define CH_CONST 1887.3506062251f   // -0.5*512*(log(2pi)+log(1e-4))
#define CY_CONST 943.6753031126f    // -0.5*256*(...)
#define LOG2E 1.4426950408889634f
#define LN2 0.6931471805599453f

__device__ __forceinline__ float fexp2(float x) { return __builtin_amdgcn_exp2f(x); }
__device__ __forceinline__ float flog2(float x) { return __builtin_amdgcn_logf(x); }
__device__ __forceinline__ float ftanh(float x) {
    x = fminf(10.f, fmaxf(-10.f, x));
    float t = fexp2(x * 2.885390081777927f);  // 2*log2(e)
    return (t - 1.f) * __builtin_amdgcn_rcpf(t + 1.f);
}
__device__ __forceinline__ float lse8v(const float* z) {
    float M = fmaxf(fmaxf(fmaxf(z[0], z[1]), fmaxf(z[2], z[3])),
                    fmaxf(fmaxf(z[4], z[5]), fmaxf(z[6], z[7])));
    float s = 0.f;
#pragma unroll
    for (int j = 0; j < 8; ++j) s += fexp2((z[j] - M) * LOG2E);
    return M + LN2 * flog2(s);
}

// ---------------- conversion: A + extended B (incl. Wt tile), no LDS ----------
// tiled index for (row m, col c): (m>>7)*98304 + (c>>3)*1024 + (m&127)*8 + (c&7)
__global__ void conv_kernel(const float* __restrict__ x, const float* __restrict__ h,
                            const float* __restrict__ Wih, const float* __restrict__ Whh,
                            const float* __restrict__ bih, const float* __restrict__ bhh,
                            const float* __restrict__ Wt, const float* __restrict__ btv,
                            f16* __restrict__ A, f16* __restrict__ Bm,
                            float* __restrict__ biasc) {
    const int tid = threadIdx.x;
    if (blockIdx.x < 6144) {  // conv_a
        const int g = blockIdx.x * 256 + tid;  // < 16384*96
        const int m = g / 96;
        const int ch = g - m * 96;
        f16x8 pk = (f16x8)(f16)0.f;
        if (m < M_REAL) {
            const int b = m / 511;
            const int t = m - b * 511;
            const int c0 = ch * 8;
            const float* src = (c0 < ND) ? x + (size_t)(b * NT + t + 1) * ND + c0
                                         : h + (size_t)(b * NT + t) * NH + (c0 - ND);
            const float4 u = ((const float4*)src)[0];
            const float4 v = ((const float4*)src)[1];
            pk[0] = (f16)u.x; pk[1] = (f16)u.y; pk[2] = (f16)u.z; pk[3] = (f16)u.w;
            pk[4] = (f16)v.x; pk[5] = (f16)v.y; pk[6] = (f16)v.z; pk[7] = (f16)v.w;
        }
        const size_t dst =
            (size_t)(m >> 7) * TILE_ELEMS + (size_t)ch * 1024 + (size_t)(m & 127) * 8;
        *(f16x8*)(A + dst) = pk;
    } else {  // conv_b over 4224 rows: [0,4096)=Wih|Whh, [4096,4160)=Wt, rest 0
        const int g = (blockIdx.x - 6144) * 256 + tid;  // < 4224*96 = 405504
        const int n = g / 96;
        const int ch = g - n * 96;
        const int c0 = ch * 8;
        f16x8 pk = (f16x8)(f16)0.f;
        const float* src = nullptr;
        if (n < 4096) {
            src = (c0 < ND) ? Wih + (size_t)n * ND + c0 : Whh + (size_t)n * NH + (c0 - ND);
        } else {
            const int c = n - 4096;
            if (c < 64 && c0 >= ND) src = Wt + (size_t)c * NH + (c0 - ND);
        }
        if (src) {
            const float4 u = ((const float4*)src)[0];
            const float4 v = ((const float4*)src)[1];
            pk[0] = (f16)u.x; pk[1] = (f16)u.y; pk[2] = (f16)u.z; pk[3] = (f16)u.w;
            pk[4] = (f16)v.x; pk[5] = (f16)v.y; pk[6] = (f16)v.z; pk[7] = (f16)v.w;
        }
        const size_t dst =
            (size_t)(n >> 7) * TILE_ELEMS + (size_t)ch * 1024 + (size_t)(n & 127) * 8;
        *(f16x8*)(Bm + dst) = pk;
        if (ch == 0)
            biasc[n] = (n < 4096) ? bih[n] + bhh[n] : ((n - 4096) < 64 ? btv[n - 4096] : 0.f);
    }
}

// ------- big GEMM (32x32x16 MFMA, R6-exact K-loop) -----------------------------
// tn<32: tanh + sq epilogue (4 slots via cross-wave LDS reduce).
// tn==32: trans epilogue — tanh + column log-softmax (shfl over i), writes Ps.
// K-loop is the R6 local optimum: single-buffer global_load_lds, A-panels
// pinned per XCD. Failed alternates: LDS-dbuf (R5), fixed-B (R7),
// reg-prefetch (R8), atomic epilogue (R9: WRITE 8x, +80 µs).
__global__ __launch_bounds__(256) void gemm_kernel(const f16* __restrict__ A,
                                                   const f16* __restrict__ Bm,
                                                   const float* __restrict__ biasc,
                                                   const float* __restrict__ sampled_h,
                                                   float* __restrict__ sq_part,
                                                   float* __restrict__ Ps) {
    __shared__ __align__(16) f16 Ash[8 * 128 * 8];
    __shared__ __align__(16) f16 Bsh[8 * 128 * 8];
    const int tid = threadIdx.x;
    const int lane = tid & 63;
    const int wave = tid >> 6;
    const int wx = wave & 1, wy = wave >> 1;
    const int xcd = blockIdx.x & 7;
    const int slot = blockIdx.x >> 3;  // 0..527
    const int tm = xcd * 16 + slot / NTN;
    const int tn = slot % NTN;
    const int m0 = tm * 128, n0 = tn * 128;
    const int l31 = lane & 31, hk = lane >> 5;

    f32x16 acc[2][2];
#pragma unroll
    for (int a = 0; a < 2; ++a)
#pragma unroll
        for (int b = 0; b < 2; ++b) acc[a][b] = (f32x16)0.f;

    for (int kk = 0; kk < RDIM; kk += 64) {
        __syncthreads();
        const size_t abase = (size_t)tm * TILE_ELEMS + (size_t)kk * 128;
        const size_t bbase = (size_t)tn * TILE_ELEMS + (size_t)kk * 128;
#pragma unroll
        for (int inst = 0; inst < 4; ++inst) {
            const int fb = inst * 256 + wave * 64;  // wave-uniform
            const f16* ga = A + abase + (size_t)(fb + lane) * 8;  // contiguous 1KB/inst
            const f16* gb = Bm + bbase + (size_t)(fb + lane) * 8;
            __builtin_amdgcn_global_load_lds(
                (const __attribute__((address_space(1))) void*)ga,
                (__attribute__((address_space(3))) void*)&Ash[fb * 8], 16, 0, 0);
            __builtin_amdgcn_global_load_lds(
                (const __attribute__((address_space(1))) void*)gb,
                (__attribute__((address_space(3))) void*)&Bsh[fb * 8], 16, 0, 0);
        }
        __syncthreads();
#pragma unroll
        for (int kc = 0; kc < 4; ++kc) {
            const int ch = kc * 2 + hk;
            f16x8 af[2], bfr[2];
#pragma unroll
            for (int mi = 0; mi < 2; ++mi)
                af[mi] = *(const f16x8*)&Ash[(ch * 128 + wy * 64 + mi * 32 + l31) * 8];
#pragma unroll
            for (int ni = 0; ni < 2; ++ni)
                bfr[ni] = *(const f16x8*)&Bsh[(ch * 128 + wx * 64 + ni * 32 + l31) * 8];
#pragma unroll
            for (int mi = 0; mi < 2; ++mi)
#pragma unroll
                for (int ni = 0; ni < 2; ++ni)
                    acc[mi][ni] = __builtin_amdgcn_mfma_f32_32x32x16_f16(af[mi], bfr[ni],
                                                                         acc[mi][ni], 0, 0, 0);
        }
    }

    // epilogue: C layout col=lane&31, row=(reg&3)+8*(reg>>2)+4*(lane>>5)
    if (tn == 32) {  // ---- trans: tanh + column log-softmax over i (c = i*8+j)
        if (wx == 0) {
            const float bt0 = biasc[4096 + l31];
            const float bt1 = biasc[4096 + 32 + l31];
#pragma unroll
            for (int mi = 0; mi < 2; ++mi) {
#pragma unroll
                for (int r = 0; r < 16; ++r) {
                    const int mg = m0 + wy * 64 + mi * 32 + (r & 3) + 8 * (r >> 2) + 4 * hk;
                    if (mg < M_REAL) {
                        const float v0 = ftanh(acc[mi][0][r] + bt0);  // c = l31 (i=0..3)
                        const float v1 = ftanh(acc[mi][1][r] + bt1);  // c = 32+l31 (i=4..7)
                        float M = fmaxf(v0, v1);
                        M = fmaxf(M, __shfl_xor(M, 8, 64));
                        M = fmaxf(M, __shfl_xor(M, 16, 64));
                        float s = fexp2((v0 - M) * LOG2E) + fexp2((v1 - M) * LOG2E);
                        s += __shfl_xor(s, 8, 64);
                        s += __shfl_xor(s, 16, 64);
                        const float lse = M + LN2 * flog2(s);
                        const int b = mg / 511, t = mg - b * 511;
                        const size_t base = (size_t)(b * NT + t + 1) * 64;
                        Ps[base + l31] = v0 - lse;
                        Ps[base + 32 + l31] = v1 - lse;
                    }
                }
            }
        }
    } else {  // ---- sq epilogue, 4 slots (cross-wx reduce via LDS)
        const int nbase = n0 + wx * 64;
        const int k0 = n0 >> 9;
        const int slot4 = (n0 >> 7) & 3;
        const float bias0 = biasc[nbase + l31];
        const float bias1 = biasc[nbase + 32 + l31];
        float rsv[2][16];
#pragma unroll
        for (int mi = 0; mi < 2; ++mi) {
#pragma unroll
            for (int r = 0; r < 16; ++r) {
                const int mg = m0 + wy * 64 + mi * 32 + (r & 3) + 8 * (r >> 2) + 4 * hk;
                float rs = 0.f;
                if (mg < M_REAL) {
                    const int bb = mg / 511;
                    const int tt = mg - bb * 511;
                    const float* tgt = sampled_h + (size_t)((bb << 9) + tt + 1) * NH;
                    const float v0 = ftanh(acc[mi][0][r] + bias0);
                    const float d0 = tgt[(nbase + l31) & 511] - v0;
                    const float v1 = ftanh(acc[mi][1][r] + bias1);
                    const float d1 = tgt[(nbase + 32 + l31) & 511] - v1;
                    rs = d0 * d0 + d1 * d1;
                }
                rs += __shfl_xor(rs, 1, 64);
                rs += __shfl_xor(rs, 2, 64);
                rs += __shfl_xor(rs, 4, 64);
                rs += __shfl_xor(rs, 8, 64);
                rs += __shfl_xor(rs, 16, 64);
                rsv[mi][r] = rs;
            }
        }
        float* ldsred = (float*)Ash;  // 128 floats, reuse (barrier first)
        __syncthreads();
        if (wx == 1 && l31 == 0) {
#pragma unroll
            for (int mi = 0; mi < 2; ++mi)
#pragma unroll
                for (int r = 0; r < 16; ++r) {
                    const int row = wy * 64 + mi * 32 + (r & 3) + 8 * (r >> 2) + 4 * hk;
                    ldsred[row] = rsv[mi][r];
                }
        }
        __syncthreads();
        if (wx == 0) {
#pragma unroll
            for (int mi = 0; mi < 2; ++mi)
#pragma unroll
                for (int r = 0; r < 16; ++r) {
                    const int row = wy * 64 + mi * 32 + (r & 3) + 8 * (r >> 2) + 4 * hk;
                    const int mg = m0 + row;
                    const float tot = rsv[mi][r] + ldsred[row];
                    if (l31 == 0 && mg < M_REAL)
                        sq_part[(size_t)(mg * 8 + k0) * 4 + slot4] = tot;
                }
        }
    }
}

// ------ post: finalize_h + s0 + pinit (512 blocks) | emission (1024 blocks) ----
__global__ __launch_bounds__(256) void post_kernel(
    const float* __restrict__ sq_part, const float* __restrict__ initials,
    const float* __restrict__ h, const float* __restrict__ y, const float* __restrict__ W1,
    const float* __restrict__ b1, const float* __restrict__ W2, const float* __restrict__ b2,
    const float* __restrict__ W3, const float* __restrict__ b3, float* __restrict__ out) {
    __shared__ __align__(16) float smem[11904];  // emission arena (47.6 KB)
    const int tid = threadIdx.x;
    if (blockIdx.x < 512) {  // finalize_h + s0 + pinit
        const int g = blockIdx.x * 256 + tid;  // < 131072
        const int b = g >> 12;
        const int t = (g >> 3) & 511;
        const int k = g & 7;
        float val;
        if (t == 0) {
            val = CH_CONST;
        } else {
            const int m = b * 511 + (t - 1);
            const float4 a = *(const float4*)&sq_part[(size_t)(m * 8 + k) * 4];
            val = CH_CONST - 5000.f * (a.x + a.y + a.z + a.w);
        }
        out[OFF_H + g] = val;
        if (g < 2048) {
            const int sb = g >> 6, c = g & 63;
            out[OFF_S + (size_t)sb * NT * 64 + c] = ((c >> 3) == (c & 7)) ? 1.f : 0.f;
        }
        if (g < 256) {
            float z[8];
#pragma unroll
            for (int j = 0; j < 8; ++j) z[j] = initials[j];
            out[OFF_PI + g] = z[g & 7] - lse8v(z);
        }
    } else {  // emission MLP + gaussian lp (phase-split)
        float* ssh = smem;           // 16*512
        float* W2sh = smem + 8192;   // 64*33
        float* h1sh = smem + 10304;  // 16*32
        float* h2sh = smem + 10816;  // 16*64
        float* red = smem + 11840;   // 16*4
        const int wv = tid >> 6;
        const int o = tid >> 3, seg = tid & 7;
        const int p0 = (blockIdx.x - 512) * 16;
        float4 w1r[16], w3r[16];
        {
            const float4* w1p = (const float4*)(W1 + (size_t)o * NH + seg * 64);
#pragma unroll
            for (int j = 0; j < 16; ++j) w1r[j] = w1p[(j + seg * 2) & 15];  // staggered
            const float4* w3p = (const float4*)(W3 + (size_t)tid * 64);
#pragma unroll
            for (int j = 0; j < 16; ++j) w3r[j] = w3p[j];
        }
        if (tid < 64) {
            for (int j = 0; j < 32; ++j) W2sh[tid * 33 + j] = W2[tid * 32 + j];
        }
        float yv[16];
#pragma unroll
        for (int pp = 0; pp < 16; ++pp) yv[pp] = y[(size_t)(p0 + pp) * ND + tid];
        const float b1r = b1[o];
        const float b2r = b2[tid & 63];
        const float b3r = b3[tid];
#pragma unroll
        for (int pp = 0; pp < 16; ++pp) {
            const float2 hv = ((const float2*)(h + (size_t)(p0 + pp) * NH))[tid];
            ssh[pp * 512 + tid * 2] = hv.x;
            ssh[pp * 512 + tid * 2 + 1] = hv.y;
        }
        __syncthreads();
#pragma unroll
        for (int pp = 0; pp < 16; ++pp) {
            const float4* s4 = (const float4*)&ssh[pp * 512 + seg * 64];
            float p = 0.f;
#pragma unroll
            for (int it = 0; it < 16; ++it) {
                const float4 sv = s4[(it + seg * 2) & 15];  // dynamic LDS idx ok
                const float4 w = w1r[it];                   // static reg idx
                p += w.x * sv.x + w.y * sv.y + w.z * sv.z + w.w * sv.w;
            }
            p += __shfl_xor(p, 1, 64);
            p += __shfl_xor(p, 2, 64);
            p += __shfl_xor(p, 4, 64);
            if (seg == 0) h1sh[pp * 32 + o] = fmaxf(p + b1r, 0.f);
        }
        __syncthreads();
        {
            const int o2 = tid & 63;
#pragma unroll
            for (int it = 0; it < 4; ++it) {
                const int pp = wv * 4 + it;
                float s = b2r;
#pragma unroll
                for (int j = 0; j < 32; ++j) s += W2sh[o2 * 33 + j] * h1sh[pp * 32 + j];
                h2sh[pp * 64 + o2] = fmaxf(s, 0.f);
            }
        }
        __syncthreads();
#pragma unroll
        for (int pp = 0; pp < 16; ++pp) {
            float s = b3r;
            const float4* h24 = (const float4*)&h2sh[pp * 64];
#pragma unroll
            for (int j = 0; j < 16; ++j) {
                const float4 w = w3r[j], hb = h24[j];
                s += w.x * hb.x + w.y * hb.y + w.z * hb.z + w.w * hb.w;
            }
            const float d = yv[pp] - s;
            float sq = d * d;
#pragma unroll
            for (int off = 32; off > 0; off >>= 1) sq += __shfl_xor(sq, off, 64);
            if ((tid & 63) == 0) red[pp * 4 + wv] = sq;
        }
        __syncthreads();
        if (tid < 16) {
            out[OFF_Y + p0 + tid] =
                CY_CONST - 5000.f * (red[tid * 4] + red[tid * 4 + 1] + red[tid * 4 + 2] +
                                     red[tid * 4 + 3]);
        }
    }
}

// ------- forward / backward scans: shfl-only + depth-8 register pipeline -------
// backward reads Ps strided (8 scalars/step, pipelined) — PsT dropped for ws.
__global__ __launch_bounds__(256) void scan_kernel(const float* __restrict__ initials,
                                                   float* __restrict__ out) {
    const float* Ps = out + OFF_S;
    const float* Ph = out + OFF_H;
    const float* Py = out + OFF_Y;
    const int lane = threadIdx.x & 63;
    const int wave = threadIdx.x >> 6;
    const int b = wave * 8 + (lane >> 3);
    const int i = lane & 7;
    const int lbase = lane & ~7;

    if (blockIdx.x == 0) {
        float z0[8];
#pragma unroll
        for (int j = 0; j < 8; ++j) z0[j] = initials[j];
        float* Fw = out + OFF_F;
        float a = (z0[i] - lse8v(z0)) + CH_CONST + Py[b * NT];
        Fw[(size_t)(b * NT) * 8 + i] = a;
        float4 cA[8], cB[8]; float cH[8], cY[8];
        float4 nA[8], nB[8]; float nH[8], nY[8];
#define FLOAD(CC, A_, B_, H_, Y_)                                                  \
        _Pragma("unroll") for (int j = 0; j < 8; ++j) {                            \
            int t = 1 + (CC) * 8 + j;                                              \
            t = t > 511 ? 511 : t;                                                 \
            const size_t p = (size_t)(b * NT + t) * 64 + i * 8;                    \
            A_[j] = *(const float4*)&Ps[p];                                        \
            B_[j] = *(const float4*)&Ps[p + 4];                                    \
            H_[j] = Ph[(size_t)(b * NT + t) * 8 + i];                              \
            Y_[j] = Py[b * NT + t];                                                \
        }
#define FSTEP(CC, A_, B_, H_, Y_)                                                  \
        _Pragma("unroll") for (int j = 0; j < 8; ++j) {                            \
            const int t = 1 + (CC) * 8 + j;                                        \
            if (t < NT) {                                                          \
                float z[8];                                                        \
                z[0] = __shfl(a, lbase + 0, 64) + A_[j].x;                         \
                z[1] = __shfl(a, lbase + 1, 64) + A_[j].y;                         \
                z[2] = __shfl(a, lbase + 2, 64) + A_[j].z;                         \
                z[3] = __shfl(a, lbase + 3, 64) + A_[j].w;                         \
                z[4] = __shfl(a, lbase + 4, 64) + B_[j].x;                         \
                z[5] = __shfl(a, lbase + 5, 64) + B_[j].y;                         \
                z[6] = __shfl(a, lbase + 6, 64) + B_[j].z;                         \
                z[7] = __shfl(a, lbase + 7, 64) + B_[j].w;                         \
                a = (H_[j] + Y_[j]) + lse8v(z);                                    \
                Fw[(size_t)(b * NT + t) * 8 + i] = a;                              \
            }                                                                      \
        }
        FLOAD(0, cA, cB, cH, cY);
        for (int c = 0; c < 64; c += 2) {
            const int c1 = c + 1;
            const int c2 = (c + 2 < 64) ? c + 2 : 63;
            FLOAD(c1, nA, nB, nH, nY);
            FSTEP(c, cA, cB, cH, cY);
            FLOAD(c2, cA, cB, cH, cY);
            FSTEP(c1, nA, nB, nH, nY);
        }
#undef FLOAD
#undef FSTEP
    } else {
        float* Bw = out + OFF_BW;
        float bv = 0.f;
        Bw[(size_t)(b * NT + NT - 1) * 8 + i] = 0.f;
        float cS[8][8], nS[8][8]; float cH[8], cY[8], nH[8], nY[8];
#define BLOAD(CC, S_, H_, Y_)                                                      \
        _Pragma("unroll") for (int j = 0; j < 8; ++j) {                            \
            int t = 510 - ((CC) * 8 + j);                                          \
            t = t < 0 ? 0 : t;                                                     \
            const size_t t1 = (size_t)(b * NT + t + 1);                            \
            _Pragma("unroll") for (int ii = 0; ii < 8; ++ii)                       \
                S_[j][ii] = Ps[t1 * 64 + ii * 8 + i];                              \
            H_[j] = Ph[t1 * 8 + i];                                                \
            Y_[j] = Py[t1];                                                        \
        }
#define BSTEP(CC, S_, H_, Y_)                                                      \
        _Pragma("unroll") for (int j = 0; j < 8; ++j) {                            \
            const int t = 510 - ((CC) * 8 + j);                                    \
            if (t >= 0) {                                                          \
                const float v = H_[j] + Y_[j] + bv;                                \
                float z[8];                                                        \
                _Pragma("unroll") for (int ii = 0; ii < 8; ++ii)                   \
                    z[ii] = __shfl(v, lbase + ii, 64) + S_[j][ii];                 \
                bv = lse8v(z);                                                     \
                Bw[(size_t)(b * NT + t) * 8 + i] = bv;                             \
            }                                                                      \
        }
        BLOAD(0, cS, cH, cY);
        for (int c = 0; c < 64; c += 2) {
            const int c1 = c + 1;
            const int c2 = (c + 2 < 64) ? c + 2 : 63;
            BLOAD(c1, nS, nH, nY);
            BSTEP(c, cS, cH, cY);
            BLOAD(c2, cS, cH, cY);
            BSTEP(c1, nS, nH, nY);
        }
#undef BLOAD
#undef BSTEP
    }
}

// ---------------- fused gamma2 (511 blocks) + gamma1 (64 blocks) ---------------
__global__ void gamma_kernel(float* __restrict__ out) {
    const float* Ps = out + OFF_S;
    const float* Ph = out + OFF_H;
    const float* Py = out + OFF_Y;
    const float* Fw = out + OFF_F;
    const float* Bw = out + OFF_BW;
    if (blockIdx.x < 511) {
        const int gidx = blockIdx.x * 256 + threadIdx.x;  // < 130816 = 32*511*8
        const int pos = gidx >> 3;                        // b*511 + t
        const int i = gidx & 7;
        const int b = pos / 511, t = pos - b * 511;
        const size_t t1 = (size_t)(b * NT + t + 1);
        const float ei = Ph[t1 * 8 + i] + Py[t1] + Bw[t1 * 8 + i];
        const float4 sa = ((const float4*)&Ps[(t1 * 8 + i) * 8])[0];
        const float4 sb = ((const float4*)&Ps[(t1 * 8 + i) * 8])[1];
        const float4 fa = ((const float4*)&Fw[(size_t)(b * NT + t) * 8])[0];
        const float4 fb = ((const float4*)&Fw[(size_t)(b * NT + t) * 8])[1];
        float z[8] = {fa.x + sa.x + ei, fa.y + sa.y + ei, fa.z + sa.z + ei, fa.w + sa.w + ei,
                      fb.x + sb.x + ei, fb.y + sb.y + ei, fb.z + sb.z + ei, fb.w + sb.w + ei};
        float M = fmaxf(fmaxf(fmaxf(z[0], z[1]), fmaxf(z[2], z[3])),
                        fmaxf(fmaxf(z[4], z[5]), fmaxf(z[6], z[7])));
        M = fmaxf(M, __shfl_xor(M, 1, 64));
        M = fmaxf(M, __shfl_xor(M, 2, 64));
        M = fmaxf(M, __shfl_xor(M, 4, 64));
        float s = 0.f;
#pragma unroll
        for (int j = 0; j < 8; ++j) s += fexp2((z[j] - M) * LOG2E);
        s += __shfl_xor(s, 1, 64);
        s += __shfl_xor(s, 2, 64);
        s += __shfl_xor(s, 4, 64);
        const float l = M + LN2 * flog2(s);
        float* G2 = out + OFF_G2;
        float4 o0 = {z[0] - l, z[1] - l, z[2] - l, z[3] - l};
        float4 o1 = {z[4] - l, z[5] - l, z[6] - l, z[7] - l};
        ((float4*)&G2[(size_t)gidx * 8])[0] = o0;
        ((float4*)&G2[(size_t)gidx * 8])[1] = o1;
    } else {
        const int pos = (blockIdx.x - 511) * 256 + threadIdx.x;  // < 16384
        const float4 fa = ((const float4*)&Fw[(size_t)pos * 8])[0];
        const float4 fb = ((const float4*)&Fw[(size_t)pos * 8])[1];
        const float4 ba = ((const float4*)&Bw[(size_t)pos * 8])[0];
        const float4 bb = ((const float4*)&Bw[(size_t)pos * 8])[1];
        float ab[8] = {fa.x + ba.x, fa.y + ba.y, fa.z + ba.z, fa.w + ba.w,
                       fb.x + bb.x, fb.y + bb.y, fb.z + bb.z, fb.w + bb.w};
        const float l = lse8v(ab);
        float* G1 = out + OFF_G1;
        float4 o0 = {ab[0] - l, ab[1] - l, ab[2] - l, ab[3] - l};
        float4 o1 = {ab[4] - l, ab[5] - l, ab[6] - l, ab[7] - l};
        ((float4*)&G1[(size_t)pos * 8])[0] = o0;
        ((float4*)&G1[(size_t)pos * 8])[1] = o1;
    }
}

extern "C" void kernel_launch(void* const* d_in, const int* in_sizes, int n_in, void* d_out,
                              int out_size, void* d_ws, size_t ws_size, hipStream_t stream) {
    const float* x = (const float*)d_in[0];
    const float* y = (const float*)d_in[1];
    const float* h = (const float*)d_in[2];
    const float* initials = (const float*)d_in[3];
    const float* Wih = (const float*)d_in[4];
    const float* Whh = (const float*)d_in[5];
    const float* bih = (const float*)d_in[6];
    const float* bhh = (const float*)d_in[7];
    const float* Wt = (const float*)d_in[8];
    const float* btv = (const float*)d_in[9];
    const float* W1 = (const float*)d_in[10];
    const float* b1 = (const float*)d_in[11];
    const float* W2 = (const float*)d_in[12];
    const float* b2 = (const float*)d_in[13];
    const float* W3 = (const float*)d_in[14];
    const float* b3 = (const float*)d_in[15];
    float* out = (float*)d_out;
    char* ws = (char*)d_ws;
    if (ws_size < (size_t)WS_NEED) return;
    f16* Aws = (f16*)(ws + WS_A);
    f16* Bws = (f16*)(ws + WS_B);
    float* biasc = (float*)(ws + WS_BIAS);
    float* sqp = (float*)(ws + WS_SQ);

    conv_kernel<<<7728, 256, 0, stream>>>(x, h, Wih, Whh, bih, bhh, Wt, btv, Aws, Bws, biasc);
    gemm_kernel<<<4224, 256, 0, stream>>>(Aws, Bws, biasc, h, sqp, out + OFF_S);
    post_kernel<<<1536, 256, 0, stream>>>(sqp, initials, h, y, W1, b1, W2, b2, W3, b3, out);
    scan_kernel<<<2, 256, 0, stream>>>(initials, out);
    gamma_kernel<<<575, 256, 0, stream>>>(out);
}

// Round 11
// 451.577 us; speedup vs baseline: 1.3394x; 1.2407x over previous
//
#include <hip/hip_runtime.h>

typedef _Float16 f16;
typedef _Float16 f16x8 __attribute__((ext_vector_type(8)));
typedef float f32x16 __attribute__((ext_vector_type(16)));

#define NB 32
#define NT 512
#define ND 256
#define NH 512
#define M_REAL 16352   // NB*(NT-1)
#define RDIM 768       // ND + NH
#define TILE_ELEMS 98304  // 96 ch * 128 rows * 8 f16 per tile
#define NTN 33            // 32 real n-tiles + 1 trans tile (cols 4096..4223)

// output offsets (floats)
#define OFF_PI 0
#define OFF_S  256
#define OFF_H  1048832
#define OFF_Y  1179904
#define OFF_G1 1196288
#define OFF_G2 1327360
#define OFF_F  2373888
#define OFF_BW 2504960

// ws offsets (bytes)
#define WS_A    0            // f16 tiled [128][96][128][8] = 25165824 B
#define WS_B    25165824     // f16 tiled [33][96][128][8]  = 6488064 B
#define WS_BIAS 31653888     // f32 [4224]
#define WS_SQ   31671296     // f32 [16384][8][4] = 2097152 B
#define WS_NEED 33768448

#define CH_CONST 1887.3506062251f   // -0.5*512*(log(2pi)+log(1e-4))
#define CY_CONST 943.6753031126f    // -0.5*256*(...)
#define LOG2E 1.4426950408889634f
#define LN2 0.6931471805599453f

__device__ __forceinline__ float fexp2(float x) { return __builtin_amdgcn_exp2f(x); }
__device__ __forceinline__ float flog2(float x) { return __builtin_amdgcn_logf(x); }
__device__ __forceinline__ float ftanh(float x) {
    x = fminf(10.f, fmaxf(-10.f, x));
    float t = fexp2(x * 2.885390081777927f);  // 2*log2(e)
    return (t - 1.f) * __builtin_amdgcn_rcpf(t + 1.f);
}
__device__ __forceinline__ float lse8v(const float* z) {
    float M = fmaxf(fmaxf(fmaxf(z[0], z[1]), fmaxf(z[2], z[3])),
                    fmaxf(fmaxf(z[4], z[5]), fmaxf(z[6], z[7])));
    float s = 0.f;
#pragma unroll
    for (int j = 0; j < 8; ++j) s += fexp2((z[j] - M) * LOG2E);
    return M + LN2 * flog2(s);
}

// -------- conv (A + extended B incl. Wt tile) | emission, one kernel ----------
// tiled index for (row m, col c): (m>>7)*98304 + (c>>3)*1024 + (m&127)*8 + (c&7)
__global__ __launch_bounds__(256) void conv_kernel(
    const float* __restrict__ x, const float* __restrict__ h, const float* __restrict__ y,
    const float* __restrict__ Wih, const float* __restrict__ Whh,
    const float* __restrict__ bih, const float* __restrict__ bhh,
    const float* __restrict__ Wt, const float* __restrict__ btv,
    const float* __restrict__ W1, const float* __restrict__ b1,
    const float* __restrict__ W2, const float* __restrict__ b2,
    const float* __restrict__ W3, const float* __restrict__ b3, f16* __restrict__ A,
    f16* __restrict__ Bm, float* __restrict__ biasc, float* __restrict__ out) {
    __shared__ __align__(16) float smem[11904];  // emission arena only
    const int tid = threadIdx.x;
    if (blockIdx.x < 6144) {  // -------- conv_a --------
        const int g = blockIdx.x * 256 + tid;  // < 16384*96
        const int m = g / 96;
        const int ch = g - m * 96;
        f16x8 pk = (f16x8)(f16)0.f;
        if (m < M_REAL) {
            const int b = m / 511;
            const int t = m - b * 511;
            const int c0 = ch * 8;
            const float* src = (c0 < ND) ? x + (size_t)(b * NT + t + 1) * ND + c0
                                         : h + (size_t)(b * NT + t) * NH + (c0 - ND);
            const float4 u = ((const float4*)src)[0];
            const float4 v = ((const float4*)src)[1];
            pk[0] = (f16)u.x; pk[1] = (f16)u.y; pk[2] = (f16)u.z; pk[3] = (f16)u.w;
            pk[4] = (f16)v.x; pk[5] = (f16)v.y; pk[6] = (f16)v.z; pk[7] = (f16)v.w;
        }
        const size_t dst =
            (size_t)(m >> 7) * TILE_ELEMS + (size_t)ch * 1024 + (size_t)(m & 127) * 8;
        *(f16x8*)(A + dst) = pk;
    } else if (blockIdx.x < 7728) {  // -------- conv_b (4224 rows) --------
        const int g = (blockIdx.x - 6144) * 256 + tid;  // < 405504
        const int n = g / 96;
        const int ch = g - n * 96;
        const int c0 = ch * 8;
        f16x8 pk = (f16x8)(f16)0.f;
        const float* src = nullptr;
        if (n < 4096) {
            src = (c0 < ND) ? Wih + (size_t)n * ND + c0 : Whh + (size_t)n * NH + (c0 - ND);
        } else {
            const int c = n - 4096;
            if (c < 64 && c0 >= ND) src = Wt + (size_t)c * NH + (c0 - ND);
        }
        if (src) {
            const float4 u = ((const float4*)src)[0];
            const float4 v = ((const float4*)src)[1];
            pk[0] = (f16)u.x; pk[1] = (f16)u.y; pk[2] = (f16)u.z; pk[3] = (f16)u.w;
            pk[4] = (f16)v.x; pk[5] = (f16)v.y; pk[6] = (f16)v.z; pk[7] = (f16)v.w;
        }
        const size_t dst =
            (size_t)(n >> 7) * TILE_ELEMS + (size_t)ch * 1024 + (size_t)(n & 127) * 8;
        *(f16x8*)(Bm + dst) = pk;
        if (ch == 0)
            biasc[n] = (n < 4096) ? bih[n] + bhh[n] : ((n - 4096) < 64 ? btv[n - 4096] : 0.f);
    } else {  // -------- emission MLP + gaussian lp --------
        float* ssh = smem;           // 16*512
        float* W2sh = smem + 8192;   // 64*33
        float* h1sh = smem + 10304;  // 16*32
        float* h2sh = smem + 10816;  // 16*64
        float* red = smem + 11840;   // 16*4
        const int wv = tid >> 6;
        const int o = tid >> 3, seg = tid & 7;
        const int p0 = (blockIdx.x - 7728) * 16;
        float4 w1r[16], w3r[16];
        {
            const float4* w1p = (const float4*)(W1 + (size_t)o * NH + seg * 64);
#pragma unroll
            for (int j = 0; j < 16; ++j) w1r[j] = w1p[(j + seg * 2) & 15];  // staggered
            const float4* w3p = (const float4*)(W3 + (size_t)tid * 64);
#pragma unroll
            for (int j = 0; j < 16; ++j) w3r[j] = w3p[j];
        }
        if (tid < 64) {
            for (int j = 0; j < 32; ++j) W2sh[tid * 33 + j] = W2[tid * 32 + j];
        }
        float yv[16];
#pragma unroll
        for (int pp = 0; pp < 16; ++pp) yv[pp] = y[(size_t)(p0 + pp) * ND + tid];
        const float b1r = b1[o];
        const float b2r = b2[tid & 63];
        const float b3r = b3[tid];
#pragma unroll
        for (int pp = 0; pp < 16; ++pp) {
            const float2 hv = ((const float2*)(h + (size_t)(p0 + pp) * NH))[tid];
            ssh[pp * 512 + tid * 2] = hv.x;
            ssh[pp * 512 + tid * 2 + 1] = hv.y;
        }
        __syncthreads();
#pragma unroll
        for (int pp = 0; pp < 16; ++pp) {
            const float4* s4 = (const float4*)&ssh[pp * 512 + seg * 64];
            float p = 0.f;
#pragma unroll
            for (int it = 0; it < 16; ++it) {
                const float4 sv = s4[(it + seg * 2) & 15];  // dynamic LDS idx ok
                const float4 w = w1r[it];                   // static reg idx
                p += w.x * sv.x + w.y * sv.y + w.z * sv.z + w.w * sv.w;
            }
            p += __shfl_xor(p, 1, 64);
            p += __shfl_xor(p, 2, 64);
            p += __shfl_xor(p, 4, 64);
            if (seg == 0) h1sh[pp * 32 + o] = fmaxf(p + b1r, 0.f);
        }
        __syncthreads();
        {
            const int o2 = tid & 63;
#pragma unroll
            for (int it = 0; it < 4; ++it) {
                const int pp = wv * 4 + it;
                float s = b2r;
#pragma unroll
                for (int j = 0; j < 32; ++j) s += W2sh[o2 * 33 + j] * h1sh[pp * 32 + j];
                h2sh[pp * 64 + o2] = fmaxf(s, 0.f);
            }
        }
        __syncthreads();
#pragma unroll
        for (int pp = 0; pp < 16; ++pp) {
            float s = b3r;
            const float4* h24 = (const float4*)&h2sh[pp * 64];
#pragma unroll
            for (int j = 0; j < 16; ++j) {
                const float4 w = w3r[j], hb = h24[j];
                s += w.x * hb.x + w.y * hb.y + w.z * hb.z + w.w * hb.w;
            }
            const float d = yv[pp] - s;
            float sq = d * d;
#pragma unroll
            for (int off = 32; off > 0; off >>= 1) sq += __shfl_xor(sq, off, 64);
            if ((tid & 63) == 0) red[pp * 4 + wv] = sq;
        }
        __syncthreads();
        if (tid < 16) {
            out[OFF_Y + p0 + tid] =
                CY_CONST - 5000.f * (red[tid * 4] + red[tid * 4 + 1] + red[tid * 4 + 2] +
                                     red[tid * 4 + 3]);
        }
    }
}

// ------- big GEMM (32x32x16 MFMA, R6-exact K-loop) -----------------------------
// Wave mapping: each wave owns a 32-row strip x full 128 cols (acc[4]) so the
// sq epilogue reduces with pure 32-lane shuffles -> 4-slot sq_part with NO
// rsv array / LDS reduce (R10's 108 VGPR + 21% occupancy regression).
// K-loop stays at R6 local optimum: single-buffer global_load_lds, A-panels
// pinned per XCD. Failed alternates: LDS-dbuf (R5), fixed-B (R7),
// reg-prefetch (R8), atomic epilogue (R9).
__global__ __launch_bounds__(256) void gemm_kernel(const f16* __restrict__ A,
                                                   const f16* __restrict__ Bm,
                                                   const float* __restrict__ biasc,
                                                   const float* __restrict__ sampled_h,
                                                   float* __restrict__ sq_part,
                                                   float* __restrict__ Ps) {
    __shared__ __align__(16) f16 Ash[8 * 128 * 8];
    __shared__ __align__(16) f16 Bsh[8 * 128 * 8];
    const int tid = threadIdx.x;
    const int lane = tid & 63;
    const int wave = tid >> 6;
    const int xcd = blockIdx.x & 7;
    const int slot = blockIdx.x >> 3;  // 0..527
    const int tm = xcd * 16 + slot / NTN;
    const int tn = slot % NTN;
    const int m0 = tm * 128, n0 = tn * 128;
    const int l31 = lane & 31, hk = lane >> 5;

    f32x16 acc[4];
#pragma unroll
    for (int a = 0; a < 4; ++a) acc[a] = (f32x16)0.f;

    for (int kk = 0; kk < RDIM; kk += 64) {
        __syncthreads();
        const size_t abase = (size_t)tm * TILE_ELEMS + (size_t)kk * 128;
        const size_t bbase = (size_t)tn * TILE_ELEMS + (size_t)kk * 128;
#pragma unroll
        for (int inst = 0; inst < 4; ++inst) {
            const int fb = inst * 256 + wave * 64;  // wave-uniform
            const f16* ga = A + abase + (size_t)(fb + lane) * 8;  // contiguous 1KB/inst
            const f16* gb = Bm + bbase + (size_t)(fb + lane) * 8;
            __builtin_amdgcn_global_load_lds(
                (const __attribute__((address_space(1))) void*)ga,
                (__attribute__((address_space(3))) void*)&Ash[fb * 8], 16, 0, 0);
            __builtin_amdgcn_global_load_lds(
                (const __attribute__((address_space(1))) void*)gb,
                (__attribute__((address_space(3))) void*)&Bsh[fb * 8], 16, 0, 0);
        }
        __syncthreads();
#pragma unroll
        for (int kc = 0; kc < 4; ++kc) {
            const int ch = kc * 2 + hk;
            const f16x8 af = *(const f16x8*)&Ash[(ch * 128 + wave * 32 + l31) * 8];
            f16x8 bfr[4];
#pragma unroll
            for (int ni = 0; ni < 4; ++ni)
                bfr[ni] = *(const f16x8*)&Bsh[(ch * 128 + ni * 32 + l31) * 8];
#pragma unroll
            for (int ni = 0; ni < 4; ++ni)
                acc[ni] = __builtin_amdgcn_mfma_f32_32x32x16_f16(af, bfr[ni], acc[ni], 0, 0, 0);
        }
    }

    // epilogue: C layout col=lane&31, row=(reg&3)+8*(reg>>2)+4*(lane>>5)
    if (tn == 32) {  // ---- trans: tanh + column log-softmax over i (c = i*8+j)
        const float bt0 = biasc[4096 + l31];
        const float bt1 = biasc[4096 + 32 + l31];
#pragma unroll
        for (int r = 0; r < 16; ++r) {
            const int mg = m0 + wave * 32 + (r & 3) + 8 * (r >> 2) + 4 * hk;
            if (mg < M_REAL) {
                const float v0 = ftanh(acc[0][r] + bt0);  // c = l31   (i = 0..3)
                const float v1 = ftanh(acc[1][r] + bt1);  // c = 32+l31 (i = 4..7)
                float M = fmaxf(v0, v1);
                M = fmaxf(M, __shfl_xor(M, 8, 64));
                M = fmaxf(M, __shfl_xor(M, 16, 64));
                float s = fexp2((v0 - M) * LOG2E) + fexp2((v1 - M) * LOG2E);
                s += __shfl_xor(s, 8, 64);
                s += __shfl_xor(s, 16, 64);
                const float lse = M + LN2 * flog2(s);
                const int b = mg / 511, t = mg - b * 511;
                const size_t base = (size_t)(b * NT + t + 1) * 64;
                Ps[base + l31] = v0 - lse;
                Ps[base + 32 + l31] = v1 - lse;
            }
        }
    } else {  // ---- sq epilogue: full-width rows per wave -> one slot, shfl only
        const int k0 = n0 >> 9;
        const int slot4 = (n0 >> 7) & 3;
        const float b0 = biasc[n0 + l31];
        const float b1v = biasc[n0 + 32 + l31];
        const float b2v = biasc[n0 + 64 + l31];
        const float b3v = biasc[n0 + 96 + l31];
#pragma unroll
        for (int r = 0; r < 16; ++r) {
            const int mg = m0 + wave * 32 + (r & 3) + 8 * (r >> 2) + 4 * hk;
            if (mg < M_REAL) {
                const int bb = mg / 511;
                const int tt = mg - bb * 511;
                const float* tgt = sampled_h + (size_t)((bb << 9) + tt + 1) * NH;
                const float d0 = tgt[(n0 + l31) & 511] - ftanh(acc[0][r] + b0);
                const float d1 = tgt[(n0 + 32 + l31) & 511] - ftanh(acc[1][r] + b1v);
                const float d2 = tgt[(n0 + 64 + l31) & 511] - ftanh(acc[2][r] + b2v);
                const float d3 = tgt[(n0 + 96 + l31) & 511] - ftanh(acc[3][r] + b3v);
                float rs = d0 * d0 + d1 * d1 + d2 * d2 + d3 * d3;
                rs += __shfl_xor(rs, 1, 64);
                rs += __shfl_xor(rs, 2, 64);
                rs += __shfl_xor(rs, 4, 64);
                rs += __shfl_xor(rs, 8, 64);
                rs += __shfl_xor(rs, 16, 64);
                if (l31 == 0) sq_part[(size_t)(mg * 8 + k0) * 4 + slot4] = rs;
            }
        }
    }
}

// ------ post: finalize_h + s0 + pinit ----
__global__ void post_kernel(const float* __restrict__ sq_part,
                            const float* __restrict__ initials, float* __restrict__ out) {
    const int g = blockIdx.x * 256 + threadIdx.x;  // < 131072
    const int b = g >> 12;
    const int t = (g >> 3) & 511;
    const int k = g & 7;
    float val;
    if (t == 0) {
        val = CH_CONST;
    } else {
        const int m = b * 511 + (t - 1);
        const float4 a = *(const float4*)&sq_part[(size_t)(m * 8 + k) * 4];
        val = CH_CONST - 5000.f * (a.x + a.y + a.z + a.w);
    }
    out[OFF_H + g] = val;
    if (g < 2048) {
        const int sb = g >> 6, c = g & 63;
        out[OFF_S + (size_t)sb * NT * 64 + c] = ((c >> 3) == (c & 7)) ? 1.f : 0.f;
    }
    if (g < 256) {
        float z[8];
#pragma unroll
        for (int j = 0; j < 8; ++j) z[j] = initials[j];
        out[OFF_PI + g] = z[g & 7] - lse8v(z);
    }
}

// ------- forward / backward scans: shfl-only + depth-8 register pipeline -------
__global__ __launch_bounds__(256) void scan_kernel(const float* __restrict__ initials,
                                                   float* __restrict__ out) {
    const float* Ps = out + OFF_S;
    const float* Ph = out + OFF_H;
    const float* Py = out + OFF_Y;
    const int lane = threadIdx.x & 63;
    const int wave = threadIdx.x >> 6;
    const int b = wave * 8 + (lane >> 3);
    const int i = lane & 7;
    const int lbase = lane & ~7;

    if (blockIdx.x == 0) {
        float z0[8];
#pragma unroll
        for (int j = 0; j < 8; ++j) z0[j] = initials[j];
        float* Fw = out + OFF_F;
        float a = (z0[i] - lse8v(z0)) + CH_CONST + Py[b * NT];
        Fw[(size_t)(b * NT) * 8 + i] = a;
        float4 cA[8], cB[8]; float cH[8], cY[8];
        float4 nA[8], nB[8]; float nH[8], nY[8];
#define FLOAD(CC, A_, B_, H_, Y_)                                                  \
        _Pragma("unroll") for (int j = 0; j < 8; ++j) {                            \
            int t = 1 + (CC) * 8 + j;                                              \
            t = t > 511 ? 511 : t;                                                 \
            const size_t p = (size_t)(b * NT + t) * 64 + i * 8;                    \
            A_[j] = *(const float4*)&Ps[p];                                        \
            B_[j] = *(const float4*)&Ps[p + 4];                                    \
            H_[j] = Ph[(size_t)(b * NT + t) * 8 + i];                              \
            Y_[j] = Py[b * NT + t];                                                \
        }
#define FSTEP(CC, A_, B_, H_, Y_)                                                  \
        _Pragma("unroll") for (int j = 0; j < 8; ++j) {                            \
            const int t = 1 + (CC) * 8 + j;                                        \
            if (t < NT) {                                                          \
                float z[8];                                                        \
                z[0] = __shfl(a, lbase + 0, 64) + A_[j].x;                         \
                z[1] = __shfl(a, lbase + 1, 64) + A_[j].y;                         \
                z[2] = __shfl(a, lbase + 2, 64) + A_[j].z;                         \
                z[3] = __shfl(a, lbase + 3, 64) + A_[j].w;                         \
                z[4] = __shfl(a, lbase + 4, 64) + B_[j].x;                         \
                z[5] = __shfl(a, lbase + 5, 64) + B_[j].y;                         \
                z[6] = __shfl(a, lbase + 6, 64) + B_[j].z;                         \
                z[7] = __shfl(a, lbase + 7, 64) + B_[j].w;                         \
                a = (H_[j] + Y_[j]) + lse8v(z);                                    \
                Fw[(size_t)(b * NT + t) * 8 + i] = a;                              \
            }                                                                      \
        }
        FLOAD(0, cA, cB, cH, cY);
        for (int c = 0; c < 64; c += 2) {
            const int c1 = c + 1;
            const int c2 = (c + 2 < 64) ? c + 2 : 63;
            FLOAD(c1, nA, nB, nH, nY);
            FSTEP(c, cA, cB, cH, cY);
            FLOAD(c2, cA, cB, cH, cY);
            FSTEP(c1, nA, nB, nH, nY);
        }
#undef FLOAD
#undef FSTEP
    } else {
        float* Bw = out + OFF_BW;
        float bv = 0.f;
        Bw[(size_t)(b * NT + NT - 1) * 8 + i] = 0.f;
        float cS[8][8], nS[8][8]; float cH[8], cY[8], nH[8], nY[8];
#define BLOAD(CC, S_, H_, Y_)                                                      \
        _Pragma("unroll") for (int j = 0; j < 8; ++j) {                            \
            int t = 510 - ((CC) * 8 + j);                                          \
            t = t < 0 ? 0 : t;                                                     \
            const size_t t1 = (size_t)(b * NT + t + 1);                            \
            _Pragma("unroll") for (int ii = 0; ii < 8; ++ii)                       \
                S_[j][ii] = Ps[t1 * 64 + ii * 8 + i];                              \
            H_[j] = Ph[t1 * 8 + i];                                                \
            Y_[j] = Py[t1];                                                        \
        }
#define BSTEP(CC, S_, H_, Y_)                                                      \
        _Pragma("unroll") for (int j = 0; j < 8; ++j) {                            \
            const int t = 510 - ((CC) * 8 + j);                                    \
            if (t >= 0) {                                                          \
                const float v = H_[j] + Y_[j] + bv;                                \
                float z[8];                                                        \
                _Pragma("unroll") for (int ii = 0; ii < 8; ++ii)                   \
                    z[ii] = __shfl(v, lbase + ii, 64) + S_[j][ii];                 \
                bv = lse8v(z);                                                     \
                Bw[(size_t)(b * NT + t) * 8 + i] = bv;                             \
            }                                                                      \
        }
        BLOAD(0, cS, cH, cY);
        for (int c = 0; c < 64; c += 2) {
            const int c1 = c + 1;
            const int c2 = (c + 2 < 64) ? c + 2 : 63;
            BLOAD(c1, nS, nH, nY);
            BSTEP(c, cS, cH, cY);
            BLOAD(c2, cS, cH, cY);
            BSTEP(c1, nS, nH, nY);
        }
#undef BLOAD
#undef BSTEP
    }
}

// ---------------- fused gamma2 (511 blocks) + gamma1 (64 blocks) ---------------
__global__ void gamma_kernel(float* __restrict__ out) {
    const float* Ps = out + OFF_S;
    const float* Ph = out + OFF_H;
    const float* Py = out + OFF_Y;
    const float* Fw = out + OFF_F;
    const float* Bw = out + OFF_BW;
    if (blockIdx.x < 511) {
        const int gidx = blockIdx.x * 256 + threadIdx.x;  // < 130816 = 32*511*8
        const int pos = gidx >> 3;                        // b*511 + t
        const int i = gidx & 7;
        const int b = pos / 511, t = pos - b * 511;
        const size_t t1 = (size_t)(b * NT + t + 1);
        const float ei = Ph[t1 * 8 + i] + Py[t1] + Bw[t1 * 8 + i];
        const float4 sa = ((const float4*)&Ps[(t1 * 8 + i) * 8])[0];
        const float4 sb = ((const float4*)&Ps[(t1 * 8 + i) * 8])[1];
        const float4 fa = ((const float4*)&Fw[(size_t)(b * NT + t) * 8])[0];
        const float4 fb = ((const float4*)&Fw[(size_t)(b * NT + t) * 8])[1];
        float z[8] = {fa.x + sa.x + ei, fa.y + sa.y + ei, fa.z + sa.z + ei, fa.w + sa.w + ei,
                      fb.x + sb.x + ei, fb.y + sb.y + ei, fb.z + sb.z + ei, fb.w + sb.w + ei};
        float M = fmaxf(fmaxf(fmaxf(z[0], z[1]), fmaxf(z[2], z[3])),
                        fmaxf(fmaxf(z[4], z[5]), fmaxf(z[6], z[7])));
        M = fmaxf(M, __shfl_xor(M, 1, 64));
        M = fmaxf(M, __shfl_xor(M, 2, 64));
        M = fmaxf(M, __shfl_xor(M, 4, 64));
        float s = 0.f;
#pragma unroll
        for (int j = 0; j < 8; ++j) s += fexp2((z[j] - M) * LOG2E);
        s += __shfl_xor(s, 1, 64);
        s += __shfl_xor(s, 2, 64);
        s += __shfl_xor(s, 4, 64);
        const float l = M + LN2 * flog2(s);
        float* G2 = out + OFF_G2;
        float4 o0 = {z[0] - l, z[1] - l, z[2] - l, z[3] - l};
        float4 o1 = {z[4] - l, z[5] - l, z[6] - l, z[7] - l};
        ((float4*)&G2[(size_t)gidx * 8])[0] = o0;
        ((float4*)&G2[(size_t)gidx * 8])[1] = o1;
    } else {
        const int pos = (blockIdx.x - 511) * 256 + threadIdx.x;  // < 16384
        const float4 fa = ((const float4*)&Fw[(size_t)pos * 8])[0];
        const float4 fb = ((const float4*)&Fw[(size_t)pos * 8])[1];
        const float4 ba = ((const float4*)&Bw[(size_t)pos * 8])[0];
        const float4 bb = ((const float4*)&Bw[(size_t)pos * 8])[1];
        float ab[8] = {fa.x + ba.x, fa.y + ba.y, fa.z + ba.z, fa.w + ba.w,
                       fb.x + bb.x, fb.y + bb.y, fb.z + bb.z, fb.w + bb.w};
        const float l = lse8v(ab);
        float* G1 = out + OFF_G1;
        float4 o0 = {ab[0] - l, ab[1] - l, ab[2] - l, ab[3] - l};
        float4 o1 = {ab[4] - l, ab[5] - l, ab[6] - l, ab[7] - l};
        ((float4*)&G1[(size_t)pos * 8])[0] = o0;
        ((float4*)&G1[(size_t)pos * 8])[1] = o1;
    }
}

extern "C" void kernel_launch(void* const* d_in, const int* in_sizes, int n_in, void* d_out,
                              int out_size, void* d_ws, size_t ws_size, hipStream_t stream) {
    const float* x = (const float*)d_in[0];
    const float* y = (const float*)d_in[1];
    const float* h = (const float*)d_in[2];
    const float* initials = (const float*)d_in[3];
    const float* Wih = (const float*)d_in[4];
    const float* Whh = (const float*)d_in[5];
    const float* bih = (const float*)d_in[6];
    const float* bhh = (const float*)d_in[7];
    const float* Wt = (const float*)d_in[8];
    const float* btv = (const float*)d_in[9];
    const float* W1 = (const float*)d_in[10];
    const float* b1 = (const float*)d_in[11];
    const float* W2 = (const float*)d_in[12];
    const float* b2 = (const float*)d_in[13];
    const float* W3 = (const float*)d_in[14];
    const float* b3 = (const float*)d_in[15];
    float* out = (float*)d_out;
    char* ws = (char*)d_ws;
    if (ws_size < (size_t)WS_NEED) return;
    f16* Aws = (f16*)(ws + WS_A);
    f16* Bws = (f16*)(ws + WS_B);
    float* biasc = (float*)(ws + WS_BIAS);
    float* sqp = (float*)(ws + WS_SQ);

    conv_kernel<<<8752, 256, 0, stream>>>(x, h, y, Wih, Whh, bih, bhh, Wt, btv, W1, b1, W2,
                                          b2, W3, b3, Aws, Bws, biasc, out);
    gemm_kernel<<<4224, 256, 0, stream>>>(Aws, Bws, biasc, h, sqp, out + OFF_S);
    post_kernel<<<512, 256, 0, stream>>>(sqp, initials, out);
    scan_kernel<<<2, 256, 0, stream>>>(initials, out);
    gamma_kernel<<<575, 256, 0, stream>>>(out);
}